// Round 1
// baseline (5055.562 us; speedup 1.0000x reference)
//
#include <hip/hip_runtime.h>
#include <math.h>

#define BDIM 8
#define SDIM 4096
#define HDIM 2048
#define EDIM 512
#define T_TEXT 512
#define VDIM (SDIM - T_TEXT)          // 3584
#define K_SEM 512
#define K_SPA 807
#define K_MIX 634
#define K_VIS (K_SEM + K_SPA + K_MIX) // 1953
#define K_OUT (T_TEXT + K_VIS)        // 2465

// ---------------- K1: summary = mean of hidden over text tokens ----------------
__global__ void k_summary(const float* __restrict__ hs, const int* __restrict__ attn,
                          const int* __restrict__ vt, float* __restrict__ summary) {
    int idx = blockIdx.x * 256 + threadIdx.x;  // b*H + h
    int b = idx / HDIM;
    const float* base = hs + (size_t)b * SDIM * HDIM + (idx % HDIM);
    float sum = 0.f; int cnt = 0;
    for (int s = 0; s < T_TEXT; ++s) {
        // text mask: valid && !visual.  vt==-1 <=> text position by construction.
        if ((attn[b * SDIM + s] > 0) && (vt[b * SDIM + s] == -1)) {
            sum += base[(size_t)s * HDIM];
            cnt++;
        }
    }
    summary[idx] = sum / (float)cnt;
}

// ---------------- K2a: tpart[t][n] = b1[n] + temb[t] @ W1[2H:2H+E] -------------
__global__ void k_tpart(const float* __restrict__ temb, const float* __restrict__ W1,
                        const float* __restrict__ b1, float* __restrict__ tpart) {
    int n = blockIdx.x * 256 + threadIdx.x;
    int t = blockIdx.y;
    float acc = b1[n];
    for (int k = 0; k < EDIM; ++k)
        acc += temb[t * EDIM + k] * W1[(size_t)(2 * HDIM + k) * HDIM + n];
    tpart[t * HDIM + n] = acc;
}

// ---------------- K2b: common[b][n] = summary[b] @ W1[H:2H] --------------------
__global__ void k_common(const float* __restrict__ summary, const float* __restrict__ W1,
                         float* __restrict__ common) {
    int n = blockIdx.x * 256 + threadIdx.x;
    int b = blockIdx.y;
    float acc = 0.f;
    for (int k = 0; k < HDIM; ++k)
        acc += summary[b * HDIM + k] * W1[(size_t)(HDIM + k) * HDIM + n];
    common[b * HDIM + n] = acc;
}

// ---------------- K3: fused GEMM(vis_h @ W1a) + bias + gelu + @W2 --------------
// A: M=B*V rows of hidden_states (rows b*4096+512+v), K=2048
// B: W1[0:2048, :], N=2048.  Output: scores[M] via atomic partial sums.
#define BM 128
#define BN 128
#define BK 16

__global__ __launch_bounds__(256) void k_gemm_score(
    const float* __restrict__ hs, const float* __restrict__ W1,
    const float* __restrict__ W2, const int* __restrict__ vt,
    const float* __restrict__ common, const float* __restrict__ tpart,
    float* __restrict__ scores)
{
    __shared__ float As[BK][BM + 4];  // transposed A tile, padded
    __shared__ float Bs[BK][BN];

    const int tid = threadIdx.x;
    const int m0 = blockIdx.x * BM;
    const int n0 = blockIdx.y * BN;
    const int b  = m0 / VDIM;          // 3584 % 128 == 0 -> block never straddles b
    const int v0 = m0 % VDIM;
    const float* Abase = hs + ((size_t)b * SDIM + T_TEXT + v0) * HDIM;

    const int tx = tid & 15, ty = tid >> 4;
    float c[8][8];
    #pragma unroll
    for (int i = 0; i < 8; ++i)
        #pragma unroll
        for (int j = 0; j < 8; ++j) c[i][j] = 0.f;

    for (int k0 = 0; k0 < HDIM; k0 += BK) {
        // stage A tile: 128 rows x 16 k, as float4, store transposed
        #pragma unroll
        for (int r = 0; r < 2; ++r) {
            int L = tid + 256 * r;
            int i = L >> 2, c4 = (L & 3) * 4;
            float4 av = *reinterpret_cast<const float4*>(Abase + (size_t)i * HDIM + k0 + c4);
            As[c4 + 0][i] = av.x; As[c4 + 1][i] = av.y;
            As[c4 + 2][i] = av.z; As[c4 + 3][i] = av.w;
        }
        // stage B tile: 16 k-rows x 128 n
        #pragma unroll
        for (int r = 0; r < 2; ++r) {
            int L = tid + 256 * r;
            int kr = L >> 5, c4 = (L & 31) * 4;
            *reinterpret_cast<float4*>(&Bs[kr][c4]) =
                *reinterpret_cast<const float4*>(W1 + (size_t)(k0 + kr) * HDIM + n0 + c4);
        }
        __syncthreads();
        #pragma unroll
        for (int kk = 0; kk < BK; ++kk) {
            float4 a0 = *reinterpret_cast<const float4*>(&As[kk][ty * 8]);
            float4 a1 = *reinterpret_cast<const float4*>(&As[kk][ty * 8 + 4]);
            float4 b0 = *reinterpret_cast<const float4*>(&Bs[kk][tx * 8]);
            float4 b1v = *reinterpret_cast<const float4*>(&Bs[kk][tx * 8 + 4]);
            float a[8] = {a0.x, a0.y, a0.z, a0.w, a1.x, a1.y, a1.z, a1.w};
            float bb[8] = {b0.x, b0.y, b0.z, b0.w, b1v.x, b1v.y, b1v.z, b1v.w};
            #pragma unroll
            for (int i = 0; i < 8; ++i)
                #pragma unroll
                for (int j = 0; j < 8; ++j) c[i][j] += a[i] * bb[j];
        }
        __syncthreads();
    }

    // epilogue: bias + exact gelu + dot with W2 -> partial score
    float partial[8];
    #pragma unroll
    for (int i = 0; i < 8; ++i) partial[i] = 0.f;
    const int my_m0 = m0 + ty * 8;
    #pragma unroll
    for (int i = 0; i < 8; ++i) {
        int vloc = v0 + ty * 8 + i;
        int tt = vt[b * SDIM + T_TEXT + vloc];
        const float* cb = common + b * HDIM;
        const float* tb = tpart + tt * HDIM;
        #pragma unroll
        for (int j = 0; j < 8; ++j) {
            int n = n0 + tx * 8 + j;
            float pre = c[i][j] + cb[n] + tb[n];
            float g = 0.5f * pre * (1.0f + erff(pre * 0.70710678118654752f));
            partial[i] += g * W2[n];
        }
    }
    #pragma unroll
    for (int i = 0; i < 8; ++i) {
        float p = partial[i];
        p += __shfl_xor(p, 1);
        p += __shfl_xor(p, 2);
        p += __shfl_xor(p, 4);
        p += __shfl_xor(p, 8);
        if (tx == 0) atomicAdd(&scores[my_m0 + i], p);
    }
}

// ---------------- K4: per-(b,type) top-k via radix bisection -------------------
__global__ void k_topk(const float* __restrict__ scores, const int* __restrict__ vt,
                       int* __restrict__ keep)
{
    __shared__ unsigned int us[VDIM];
    __shared__ unsigned int red[256];
    int g = blockIdx.x, b = g / 3, t = g % 3;
    int k = (t == 0) ? K_SEM : (t == 1) ? K_SPA : K_MIX;
    int tid = threadIdx.x;

    for (int v = tid; v < VDIM; v += 256) {
        float s = scores[b * VDIM + v];
        float m = (vt[b * SDIM + T_TEXT + v] == t) ? s : -3.402823466e38f;
        unsigned int u = __float_as_uint(m);
        us[v] = (u & 0x80000000u) ? ~u : (u | 0x80000000u);  // order-preserving map
    }
    __syncthreads();

    unsigned int lo = 0u, hi = 0xFFFFFFFFu;
    while (lo < hi) {
        unsigned int mid = (unsigned int)(((unsigned long long)lo + hi + 1ull) >> 1);
        unsigned int cnt = 0;
        for (int v = tid; v < VDIM; v += 256) cnt += (us[v] >= mid);
        red[tid] = cnt; __syncthreads();
        for (int ofs = 128; ofs > 0; ofs >>= 1) {
            if (tid < ofs) red[tid] += red[tid + ofs];
            __syncthreads();
        }
        unsigned int total = red[0]; __syncthreads();
        if (total >= (unsigned int)k) lo = mid; else hi = mid - 1;
    }
    unsigned int T = lo;  // k-th largest mapped value

    unsigned int cgt = 0;
    for (int v = tid; v < VDIM; v += 256) cgt += (us[v] > T);
    red[tid] = cgt; __syncthreads();
    for (int ofs = 128; ofs > 0; ofs >>= 1) {
        if (tid < ofs) red[tid] += red[tid + ofs];
        __syncthreads();
    }
    int need_eq = k - (int)red[0];  // how many ties to keep (smallest index first)

    for (int v = tid; v < VDIM; v += 256) {
        unsigned int u = us[v];
        if (u > T) keep[b * VDIM + v] = 1;
        else if (u == T) {
            int r = 0;
            for (int j = 0; j < v; ++j) r += (us[j] == T);
            if (r < need_eq) keep[b * VDIM + v] = 1;
        }
    }
}

// ---------------- K5: compact kept indices -> merged (sorted) ------------------
__global__ void k_compact(const int* __restrict__ keep, int* __restrict__ merged)
{
    int b = blockIdx.x, tid = threadIdx.x;
    __shared__ int lds[256];
    int v0 = tid * 14;  // 256*14 == 3584
    int cnt = 0;
    for (int q = 0; q < 14; ++q) cnt += keep[b * VDIM + v0 + q];
    lds[tid] = cnt; __syncthreads();
    if (tid == 0) {
        int tot = 0;
        for (int i = 0; i < 256; ++i) { int tmp = lds[i]; lds[i] = tot; tot += tmp; }
    }
    __syncthreads();
    int r = lds[tid];
    for (int q = 0; q < 14; ++q) {
        int v = v0 + q;
        if (keep[b * VDIM + v]) { merged[b * K_OUT + T_TEXT + r] = T_TEXT + v; r++; }
    }
    for (int j = tid; j < T_TEXT; j += 256) merged[b * K_OUT + j] = j;
}

// ---------------- K6: gather all outputs (written as float32) ------------------
__global__ void k_outputs(const float* __restrict__ hs, const int* __restrict__ pos,
                          const int* __restrict__ vt, const int* __restrict__ merged,
                          float* __restrict__ out)
{
    int j = blockIdx.x, b = blockIdx.y, tid = threadIdx.x;
    int src = merged[b * K_OUT + j];
    const float* srcrow = hs + ((size_t)b * SDIM + src) * HDIM;
    float* dst = out + ((size_t)b * K_OUT + j) * HDIM;
    #pragma unroll
    for (int r = 0; r < 2; ++r) {
        int cidx = (tid + 256 * r) * 4;
        *reinterpret_cast<float4*>(dst + cidx) =
            *reinterpret_cast<const float4*>(srcrow + cidx);
    }
    const size_t o1 = (size_t)BDIM * K_OUT * HDIM;       // pruned_attn
    const size_t o2 = o1 + (size_t)BDIM * K_OUT;         // pruned_pos (3,B,K_OUT)
    const size_t o3 = o2 + (size_t)3 * BDIM * K_OUT;     // pruned_vmask
    const size_t o4 = o3 + (size_t)BDIM * K_OUT;         // pruned_vtypes
    const size_t o5 = o4 + (size_t)BDIM * K_OUT;         // merged
    if (tid < 3) {
        out[o2 + (size_t)tid * BDIM * K_OUT + b * K_OUT + j] =
            (float)pos[(size_t)tid * BDIM * SDIM + b * SDIM + src];
    }
    if (tid == 0) {
        int tv = vt[b * SDIM + src];
        out[o1 + b * K_OUT + j] = 1.0f;
        out[o3 + b * K_OUT + j] = (tv != -1) ? 1.0f : 0.0f;
        out[o4 + b * K_OUT + j] = (float)tv;
        out[o5 + b * K_OUT + j] = (float)src;
    }
}

extern "C" void kernel_launch(void* const* d_in, const int* in_sizes, int n_in,
                              void* d_out, int out_size, void* d_ws, size_t ws_size,
                              hipStream_t stream) {
    const float* hs   = (const float*)d_in[0];
    const int*   attn = (const int*)d_in[1];
    const int*   pos  = (const int*)d_in[2];
    // d_in[3] = visual_token_mask (bool) — not used; vt==-1 is its exact complement
    const int*   vt   = (const int*)d_in[4];
    const float* temb = (const float*)d_in[5];
    const float* W1   = (const float*)d_in[6];
    const float* b1   = (const float*)d_in[7];
    const float* W2   = (const float*)d_in[8];
    float* out = (float*)d_out;

    // workspace layout (bytes)
    char* ws = (char*)d_ws;
    float* scores  = (float*)(ws + 0);                 // 28672 f32
    int*   keep    = (int*)  (ws + 114688);            // 28672 i32
    float* summary = (float*)(ws + 229376);            // 8*2048 f32
    float* common  = (float*)(ws + 294912);            // 8*2048 f32
    float* tpart   = (float*)(ws + 360448);            // 3*2048 f32
    int*   merged  = (int*)  (ws + 385024);            // 8*2465 i32

    hipMemsetAsync(d_ws, 0, 229376, stream);  // zero scores + keep

    k_summary<<<dim3((BDIM * HDIM) / 256), 256, 0, stream>>>(hs, attn, vt, summary);
    k_tpart<<<dim3(HDIM / 256, 3), 256, 0, stream>>>(temb, W1, b1, tpart);
    k_common<<<dim3(HDIM / 256, BDIM), 256, 0, stream>>>(summary, W1, common);
    k_gemm_score<<<dim3((BDIM * VDIM) / BM, HDIM / BN), 256, 0, stream>>>(
        hs, W1, W2, vt, common, tpart, scores);
    k_topk<<<24, 256, 0, stream>>>(scores, vt, keep);
    k_compact<<<BDIM, 256, 0, stream>>>(keep, merged);
    k_outputs<<<dim3(K_OUT, BDIM), 256, 0, stream>>>(hs, pos, vt, merged, out);
}